// Round 1
// 289.951 us; speedup vs baseline: 1.1159x; 1.1159x over previous
//
#include <hip/hip_runtime.h>

#define NPROJ 180
#define PHALF 90
#define DH 192
#define DW 384
#define VN 96
#define ZPER 4
#define TCOLS 65                     // 65 u columns: u0l in [2,60] -> u0l+1 <= 64 in-window
#define TROWS 14
#define TENT (TCOLS * TROWS)         // 910 live entries
#define TPAD 1024                    // 4x256 unguarded staging; rows 14/15 are benign in-detector reads
#define PSTRIDE (DH * DW)
#define BSTRIDE (NPROJ * DH * DW)

typedef float v2f __attribute__((ext_vector_type(2)));

// r10: batch-interleaved non-redundant LDS tile + double buffer.
// Entry(v,u) = (b0[v][u], b1[v][u]) v2f. vs r9's redundant u-pair layout:
//  - ds_writes/thread/proj 7 -> 4, staged global bytes halved
//  - row stride 65 entries = 130 dwords == 2 (mod 32 banks): same-u0l lanes
//    on different rows hit distinct banks (vi in [1,12] < 16) -> conflict-free
//  - both batches packed in one v2f through the whole bilinear -> v_pk f32
//  - two 8KB buffers -> ONE barrier/proj (write buf[i&1]; prefetch; barrier;
//    sample). r9 needed 2 barriers with its single buffer.
// Grid/anchors/window identical to r9 (all bounds r7-proven): iu0=floor(uc)-31,
// iv0=floor(vc)-6, u0l in [2,60], vi in [1,11]; reads <= entry 841 < 910.
__global__ __launch_bounds__(256, 6) void cone_bp(
    const float* __restrict__ sino,   // [B, P, H, W]
    const float* __restrict__ mats,   // [P, 3, 4]
    float* __restrict__ out)          // [B, Z, Y, X]
{
    __shared__ v2f tile[2][TPAD];     // 16 KB
    __shared__ int2 anch[PHALF];      // 720 B anchor table

    const int tid = threadIdx.x;
    // 8x8 per-wave lane map (r7-proven)
    const int x = blockIdx.x * 32 + ((tid & 7) | ((tid >> 6) << 3));
    const int y = blockIdx.y * 8 + ((tid >> 3) & 7);
    const int half = (blockIdx.z >= 24) ? 1 : 0;
    const int zc = blockIdx.z - 24 * half;
    const int pbase = half * PHALF;

    const float xw = (float)x - 47.5f;
    const float yw = (float)y - 47.5f;
    const float zw0 = (float)(zc * ZPER) - 47.5f;

    // block-center world coords (tile anchoring)
    const float xwc = (float)(blockIdx.x * 32) - 32.0f;
    const float ywc = (float)(blockIdx.y * 8) - 44.0f;
    const float zwc = (float)(zc * ZPER) - 46.0f;

    const float4* __restrict__ M = (const float4*)mats;

    // ---- anchor table: one projection per thread, once ----
    if (tid < PHALF) {
        int p = pbase + tid;
        float4 a0 = M[p * 3 + 0];
        float4 a1 = M[p * 3 + 1];
        float4 a2 = M[p * 3 + 2];
        float unc = fmaf(a0.x, xwc, fmaf(a0.y, ywc, a0.w));
        float vnc = fmaf(a1.x, xwc, fmaf(a1.y, ywc, fmaf(a1.z, zwc, a1.w)));
        float wc  = fmaf(a2.x, xwc, fmaf(a2.y, ywc, a2.w));
        float rwc = __builtin_amdgcn_rcpf(wc);
        anch[tid] = make_int2((int)floorf(unc * rwc) - 31,
                              (int)floorf(vnc * rwc) - 6);
    }

    // ---- staging map: loop-invariant BYTE offsets within a projection ----
    int VgB[4];
#pragma unroll
    for (int k = 0; k < 4; ++k) {
        int li = tid + 256 * k;
        int row = li / TCOLS;            // compiler magic-mul, once
        int col = li - row * TCOLS;
        VgB[k] = (row * DW + col) * 4;
    }

    __syncthreads();    // anchor table ready

    // ---- preload proj pbase into registers ----
    int cu, cv;         // anchor of the projection currently in g[]
    {
        int2 a = anch[0];
        cu = __builtin_amdgcn_readfirstlane(a.x);
        cv = __builtin_amdgcn_readfirstlane(a.y);
    }
    v2f g[4];
    {
        const char* p0 = (const char*)(sino + pbase * PSTRIDE + cv * DW + cu);
        const char* p1 = p0 + (size_t)BSTRIDE * 4;
#pragma unroll
        for (int k = 0; k < 4; ++k) {
            g[k].x = *(const float*)(p0 + VgB[k]);
            g[k].y = *(const float*)(p1 + VgB[k]);
        }
    }

    v2f acc[ZPER];
#pragma unroll
    for (int k = 0; k < ZPER; ++k) acc[k] = (v2f)(0.0f);

    auto body = [&](int i, v2f* __restrict__ buf) {
        // ---- stage proj i (in g) into buf; vmcnt drained by prior overlap ----
#pragma unroll
        for (int k = 0; k < 4; ++k)
            buf[tid + 256 * k] = g[k];
        const float nfu = -(float)cu;        // sampling anchor (this proj)
        const float nfv = -(float)cv;

        // ---- issue p+1 staging loads BEFORE barrier+sampling ----
        if (i + 1 < PHALF) {
            int2 a = anch[i + 1];
            cu = __builtin_amdgcn_readfirstlane(a.x);
            cv = __builtin_amdgcn_readfirstlane(a.y);
            const char* p0 = (const char*)(sino
                + (pbase + i + 1) * PSTRIDE + cv * DW + cu);
            const char* p1 = p0 + (size_t)BSTRIDE * 4;
#pragma unroll
            for (int k = 0; k < 4; ++k) {
                g[k].x = *(const float*)(p0 + VgB[k]);
                g[k].y = *(const float*)(p1 + VgB[k]);
            }
        }

        __syncthreads();   // buf staged; other waves done writing; safe to read

        // ---- sample projection pbase+i (both batches packed in v2f) ----
        const int p = pbase + i;
        float4 r0 = M[p * 3 + 0];
        float4 r1 = M[p * 3 + 1];
        float4 r2 = M[p * 3 + 2];
        float un  = fmaf(r0.x, xw, fmaf(r0.y, yw, r0.w));
        float vn0 = fmaf(r1.x, xw, fmaf(r1.y, yw, r1.w));
        float w   = fmaf(r2.x, xw, fmaf(r2.y, yw, r2.w));
        float rw  = __builtin_amdgcn_rcpf(w);
        float iw2 = rw * rw;                         // FDK 1/w^2
        float ul  = fmaf(un, rw, nfu);               // tile-local u
        float uf  = floorf(ul);
        float fu  = ul - uf;
        int   u0l = (int)uf;
        float vb  = fmaf(fmaf(r1.z, zw0, vn0), rw, nfv);
        float dv  = r1.z * rw;

        // phase 1: entry offsets + fv
        int   o[ZPER];
        float fv[ZPER];
#pragma unroll
        for (int k = 0; k < ZPER; ++k) {
            float v  = fmaf(dv, (float)k, vb);
            float vf = floorf(v);
            fv[k] = v - vf;
            o[k] = (int)vf * TCOLS + u0l;
        }
        // phase 2: all LDS reads (mergeable ds_read2_b64: offsets {0,1},{65,66})
        v2f E00[ZPER], E01[ZPER], E10[ZPER], E11[ZPER];
#pragma unroll
        for (int k = 0; k < ZPER; ++k) {
            E00[k] = buf[o[k]];
            E01[k] = buf[o[k] + 1];
            E10[k] = buf[o[k] + TCOLS];
            E11[k] = buf[o[k] + TCOLS + 1];
        }
        // phase 3: fully packed bilinear + accumulate (both batches per op)
#pragma unroll
        for (int k = 0; k < ZPER; ++k) {
            v2f F0 = E00[k] + (E10[k] - E00[k]) * fv[k];
            v2f F1 = E01[k] + (E11[k] - E01[k]) * fv[k];
            v2f H  = F0 + (F1 - F0) * fu;
            acc[k] += H * iw2;
        }
    };

    // unrolled-by-2 so the buffer parity is a compile-time imm offset
    for (int i = 0; i < PHALF; i += 2) {
        body(i,     tile[0]);
        body(i + 1, tile[1]);
    }

    // ---- merge: exactly 2 blocks per voxel -> order-independent fp32 add ----
    const int zbase = zc * ZPER;
#pragma unroll
    for (int k = 0; k < ZPER; ++k) {
        unsafeAtomicAdd(&out[(((size_t)(zbase + k)) * VN + y) * VN + x],
                        acc[k].x);
        unsafeAtomicAdd(&out[(((size_t)(VN + zbase + k)) * VN + y) * VN + x],
                        acc[k].y);
    }
}

extern "C" void kernel_launch(void* const* d_in, const int* in_sizes, int n_in,
                              void* d_out, int out_size, void* d_ws, size_t ws_size,
                              hipStream_t stream) {
    const float* sino = (const float*)d_in[0];   // [2,180,192,384,1] fp32
    const float* mats = (const float*)d_in[1];   // [180,3,4] fp32
    float* out = (float*)d_out;                  // [2,96,96,96,1] fp32

    // d_out is poisoned before every launch; atomic merge needs zeros
    hipMemsetAsync(out, 0, (size_t)out_size * sizeof(float), stream);

    // grid: 3 x-tiles, 12 y-tiles, 24 z-chunks x 2 projection halves
    dim3 grid(VN / 32, VN / 8, 48), block(256);
    hipLaunchKernelGGL(cone_bp, grid, block, 0, stream, sino, mats, out);
}